// Round 8
// baseline (286.420 us; speedup 1.0000x reference)
//
#include <hip/hip_runtime.h>
#include <stdint.h>

typedef short bf16x8 __attribute__((ext_vector_type(8)));
typedef float f32x4 __attribute__((ext_vector_type(4)));
typedef unsigned int uint4v __attribute__((ext_vector_type(4)));
typedef unsigned short ushort4v __attribute__((ext_vector_type(4)));
typedef float float4v __attribute__((ext_vector_type(4)));

#define MROWS 18464      // 32*577
#define MPAD  18560      // 145*128
#define SEQ   577
#define CDIM  1024
#define SPAD  640
#define W1ELEMS (2048*1024)
#define W2ELEMS (1024*1024)
#define SQC 0.42466089f   // sqrt(0.125 * log2(e)); applied to q AND k (same buffer)

__device__ __forceinline__ unsigned short f2bf(float f) {
  unsigned int u = __float_as_uint(f);
  u += 0x7fffu + ((u >> 16) & 1u);   // RNE
  return (unsigned short)(u >> 16);
}

__device__ __forceinline__ void load_lds16(const void* g, void* lds) {
  __builtin_amdgcn_global_load_lds(
      (const __attribute__((address_space(1))) unsigned int*)(uint64_t)(uintptr_t)g,
      (__attribute__((address_space(3))) unsigned int*)(unsigned int)(uintptr_t)lds,
      16, 0, 0);
}

// ---------------- LayerNorm: x fp32 -> z bf16; pad rows zeroed ----------------
__global__ __launch_bounds__(256) void ln_kernel(const float* __restrict__ x,
                                                 const float* __restrict__ g,
                                                 const float* __restrict__ b,
                                                 unsigned short* __restrict__ z) {
  const int row = blockIdx.x;
  const int t = threadIdx.x;
  unsigned short* zp = z + (size_t)row * CDIM + t * 4;
  if (row >= MROWS) { *(ushort4v*)zp = (ushort4v)0; return; }
  const float4v v = *(const float4v*)(x + (size_t)row * CDIM + t * 4);
  float s  = v[0] + v[1] + v[2] + v[3];
  float ss = v[0]*v[0] + v[1]*v[1] + v[2]*v[2] + v[3]*v[3];
  #pragma unroll
  for (int off = 1; off < 64; off <<= 1) { s += __shfl_xor(s, off); ss += __shfl_xor(ss, off); }
  __shared__ float rs[4], rss[4];
  const int w = t >> 6, l = t & 63;
  if (l == 0) { rs[w] = s; rss[w] = ss; }
  __syncthreads();
  s = rs[0] + rs[1] + rs[2] + rs[3];
  ss = rss[0] + rss[1] + rss[2] + rss[3];
  const float mu = s * (1.0f / CDIM);
  const float var = ss * (1.0f / CDIM) - mu * mu;
  const float rstd = rsqrtf(var + 1e-5f);
  const float4v gv = *(const float4v*)(g + t * 4);
  const float4v bv = *(const float4v*)(b + t * 4);
  ushort4v o;
  #pragma unroll
  for (int j = 0; j < 4; ++j) o[j] = f2bf((v[j] - mu) * rstd * gv[j] + bv[j]);
  *(ushort4v*)zp = o;
}

// -------- pack+convert weights + zero vt's seq-pad columns --------
__global__ __launch_bounds__(256) void conv_kernel(const float* __restrict__ w_in,
                                                   const float* __restrict__ w_out,
                                                   unsigned short* __restrict__ wqv,
                                                   unsigned short* __restrict__ wo,
                                                   unsigned short* __restrict__ vt) {
  const int idx = blockIdx.x * 256 + threadIdx.x;
  const int e = idx * 4;
  if (e < W1ELEMS) {
    const int row = e >> 10;
    const int srow = row < 1024 ? row : row + 1024;
    const float4v v = *(const float4v*)(w_in + (size_t)srow * 1024 + (e & 1023));
    ushort4v o;
    #pragma unroll
    for (int j = 0; j < 4; ++j) o[j] = f2bf(v[j]);
    *(ushort4v*)(wqv + e) = o;
  } else if (e < W1ELEMS + W2ELEMS) {
    const int e2 = e - W1ELEMS;
    const float4v v = *(const float4v*)(w_out + e2);
    ushort4v o;
    #pragma unroll
    for (int j = 0; j < 4; ++j) o[j] = f2bf(v[j]);
    *(ushort4v*)(wo + e2) = o;
  } else {
    // zero vt[row][576..640) for all 32768 rows
    const int pidx = idx - (W1ELEMS + W2ELEMS) / 4;   // 0..262143
    const int ic = pidx >> 3, part = pidx & 7;
    *(uint4v*)(vt + (size_t)ic * SPAD + 576 + part * 8) = (uint4v)0u;
  }
}

// ---------------- GEMM: D[m][n] = sum_k A[m][k]*B[n][k] (+bias) ----------------
// 128x128 tile, BK=64, 4 waves. 3-slot LDS ring (96KB), depth-2 prefetch with
// COUNTED vmcnt(8) + raw s_barrier — stage loads stay in flight across barriers
// (T4). 1160 blocks, panel-major XCD-chunked map (FETCH-proven in R7).
// MODE 0: q out bf16 xSQC.  MODE 1: proj out fp32.  MODE 2: v^T out.
template<int MODE>
__global__ __launch_bounds__(256) void gemm_kernel(const unsigned short* __restrict__ A,
                                                   const unsigned short* __restrict__ B,
                                                   const float* __restrict__ bias,
                                                   void* __restrict__ outp) {
  __shared__ char smem[98304];  // slot s at s*32768: A @+0 (16KB), B @+16384
  const int t = threadIdx.x;
  const int w = t >> 6, l = t & 63;
  const int L = (blockIdx.x & 7) * 145 + (blockIdx.x >> 3);   // bijective, 1160=8*145
  const int p = L >> 3, c = L & 7;
  const int m0 = (MODE == 2) ? c * 128 : p * 128;
  const int n0 = (MODE == 2) ? p * 128 : c * 128;
  const int wr = w >> 1, wc = w & 1;
  const int g4 = (l >> 4) * 4;
  const int fr = l & 15;

  f32x4 acc[4][4];
  #pragma unroll
  for (int i = 0; i < 4; ++i)
    #pragma unroll
    for (int j = 0; j < 4; ++j) acc[i][j] = (f32x4)0.0f;

  // staging addressing: 128B rows (BK=64), 8 rows per gload, pre-swizzled source
  const int srow = l >> 3;
  const int scol = ((((l & 7) * 16) ^ ((srow & 7) << 4)) >> 1);
  const int fb = (l >> 4) * 16;
  const int sw = (l & 7) << 4;

  const unsigned short* Ab = A + (size_t)(m0 + w * 32 + srow) * 1024 + scol;
  const unsigned short* Bb = B + (size_t)(n0 + w * 32 + srow) * 1024 + scol;

  // STAGE(kt, slot): 8 gload_lds per wave (4 A + 4 B)
  #define STAGE(kt, slot)                                                        \
    {                                                                            \
      char* const base_ = smem + (slot) * 32768 + (w * 32) * 128;                \
      const int k0_ = (kt) * 64;                                                 \
      _Pragma("unroll")                                                          \
      for (int c2 = 0; c2 < 4; ++c2) {                                           \
        load_lds16(Ab + (size_t)(c2 * 8) * 1024 + k0_, base_ + c2 * 1024);       \
        load_lds16(Bb + (size_t)(c2 * 8) * 1024 + k0_, base_ + 16384 + c2 * 1024);\
      }                                                                          \
    }

  STAGE(0, 0)
  STAGE(1, 1)

  for (int kb = 0; kb < 16; ++kb) {
    // certify tile kb landed; keep tile kb+1's 8 loads in flight across barrier
    if (kb < 15) { asm volatile("s_waitcnt vmcnt(8)" ::: "memory"); }
    else         { asm volatile("s_waitcnt vmcnt(0)" ::: "memory"); }
    __builtin_amdgcn_sched_barrier(0);
    __builtin_amdgcn_s_barrier();

    const char* Abuf = smem + (kb % 3) * 32768;
    const char* Bbuf = Abuf + 16384;
    #pragma unroll
    for (int kk = 0; kk < 2; ++kk) {
      bf16x8 af[4], bf[4];
      #pragma unroll
      for (int i = 0; i < 4; ++i)
        af[i] = *(const bf16x8*)(Abuf + (wr * 64 + i * 16 + fr) * 128 + ((kk * 64 + fb) ^ sw));
      #pragma unroll
      for (int j = 0; j < 4; ++j)
        bf[j] = *(const bf16x8*)(Bbuf + (wc * 64 + j * 16 + fr) * 128 + ((kk * 64 + fb) ^ sw));
      #pragma unroll
      for (int i = 0; i < 4; ++i)
        #pragma unroll
        for (int j = 0; j < 4; ++j)
          acc[i][j] = __builtin_amdgcn_mfma_f32_16x16x32_bf16(af[i], bf[j], acc[i][j], 0, 0, 0);
    }

    if (kb < 14) STAGE(kb + 2, (kb + 2) % 3)
  }
  #undef STAGE

  __syncthreads();  // loop done, nothing outstanding; epilogue reuses smem

  if constexpr (MODE == 0) {  // q epilogue: single pass [128][136] b16 = 34816B
    unsigned short* sm = (unsigned short*)smem;
    float bcol[4];
    #pragma unroll
    for (int j = 0; j < 4; ++j) bcol[j] = bias[n0 + wc * 64 + j * 16 + fr];
    #pragma unroll
    for (int i = 0; i < 4; ++i)
      #pragma unroll
      for (int j = 0; j < 4; ++j)
        #pragma unroll
        for (int r = 0; r < 4; ++r)
          sm[(wr * 64 + i * 16 + g4 + r) * 136 + wc * 64 + j * 16 + fr] =
              f2bf((acc[i][j][r] + bcol[j]) * SQC);
    __syncthreads();
    #pragma unroll
    for (int it = 0; it < 8; ++it) {
      const int cid = it * 256 + t;
      const int row = cid >> 4, ch = cid & 15;
      *(uint4v*)((unsigned short*)outp + (size_t)(m0 + row) * 1024 + n0 + ch * 8) =
          *(const uint4v*)(sm + row * 136 + ch * 8);
    }
  } else if constexpr (MODE == 1) {  // proj fp32: single pass [128][132] f32 = 67584B
    float* smf = (float*)smem;
    float bcol[4];
    #pragma unroll
    for (int j = 0; j < 4; ++j) bcol[j] = bias[n0 + wc * 64 + j * 16 + fr];
    #pragma unroll
    for (int i = 0; i < 4; ++i)
      #pragma unroll
      for (int j = 0; j < 4; ++j)
        #pragma unroll
        for (int r = 0; r < 4; ++r)
          smf[(wr * 64 + i * 16 + g4 + r) * 132 + wc * 64 + j * 16 + fr] =
              acc[i][j][r] + bcol[j];
    __syncthreads();
    float* o = (float*)outp;
    #pragma unroll
    for (int it = 0; it < 16; ++it) {
      const int cid = it * 256 + t;
      const int row = cid >> 5, ch = cid & 31;
      const int grow = m0 + row;
      if (grow < MROWS)
        *(float4v*)(o + (size_t)grow * 1024 + n0 + ch * 4) =
            *(const float4v*)(smf + row * 132 + ch * 4);
    }
  } else {  // MODE 2: rows = channels, cols = tokens; single pass [128][136] b16
    unsigned short* sm = (unsigned short*)smem;
    float brow[4][4];
    #pragma unroll
    for (int i = 0; i < 4; ++i)
      #pragma unroll
      for (int r = 0; r < 4; ++r) brow[i][r] = bias[m0 + wr * 64 + i * 16 + g4 + r];
    #pragma unroll
    for (int i = 0; i < 4; ++i)
      #pragma unroll
      for (int j = 0; j < 4; ++j)
        #pragma unroll
        for (int r = 0; r < 4; ++r)
          sm[(wr * 64 + i * 16 + g4 + r) * 136 + wc * 64 + j * 16 + fr] =
              f2bf(acc[i][j][r] + brow[i][r]);
    __syncthreads();
    unsigned short* o = (unsigned short*)outp;
    const int col = t & 127;
    const int rbase = t >> 7;   // 0 or 1
    const int token = n0 + col;
    if (token < MROWS) {
      const unsigned int nimg = (unsigned int)token / 577u;
      const int s = token - (int)(nimg * 577u);
      unsigned short* op = o + ((size_t)nimg * 1024 + m0 + rbase) * SPAD + s;
      const unsigned short* sp = sm + rbase * 136 + col;
      #pragma unroll 8
      for (int it = 0; it < 64; ++it)
        op[(size_t)it * 2 * SPAD] = sp[it * 2 * 136];
    }
  }
}

// ---------------- flash attention, k = q ('qq'), no-max softmax ----------------
// QBLK=128: each wave owns 2x16 q-rows; K/V LDS fragments read ONCE feed both
// halves. Double-buffered staging. 1-D grid 2560, XCD-chunked.
__global__ __launch_bounds__(256) void attn_kernel(const unsigned short* __restrict__ qbuf,
                                                   const unsigned short* __restrict__ vt,
                                                   unsigned short* __restrict__ out) {
  __shared__ char smem[32768];  // buf b at b*16384: K 8KB, V^T 8KB
  const int t = threadIdx.x, w = t >> 6, l = t & 63;
  const int g = l >> 4, fr = l & 15;
  const int bid = blockIdx.x;
  const int xcd = bid & 7, idx = bid >> 3;
  const int nhl = idx / 5;
  const int qb = idx - nhl * 5;
  const int nh = xcd * 64 + nhl;
  const int n = nh >> 4, h = nh & 15;
  const size_t rowbase = (size_t)n * SEQ;
  const int sw = (l & 7) << 4;

  bf16x8 bq[2][2];
  #pragma unroll
  for (int half = 0; half < 2; ++half) {
    const unsigned short* qp =
        qbuf + (rowbase + qb * 128 + half * 64 + w * 16 + fr) * 1024 + h * 64 + g * 8;
    bq[half][0] = *(const bf16x8*)qp;
    bq[half][1] = *(const bf16x8*)(qp + 32);
  }

  const int srow = l >> 3;
  const int scolE = ((((l & 7) * 16) ^ ((srow & 7) << 4)) >> 1);
  const unsigned short* ksrc = qbuf + (rowbase + w * 16 + srow) * 1024 + h * 64 + scolE;
  const unsigned short* vsrc = vt + ((size_t)nh * 64 + w * 16 + srow) * SPAD + scolE;

  f32x4 acc[2][4];
  #pragma unroll
  for (int half = 0; half < 2; ++half)
    #pragma unroll
    for (int cf = 0; cf < 4; ++cf) acc[half][cf] = (f32x4)0.0f;
  float l_run[2] = {0.0f, 0.0f};

  {
    char* kdst = smem + (w * 16) * 128;
    char* vdst = smem + 8192 + (w * 16) * 128;
    load_lds16(ksrc, kdst);
    load_lds16(ksrc + (size_t)8 * 1024, kdst + 1024);
    load_lds16(vsrc, vdst);
    load_lds16(vsrc + 8 * SPAD, vdst + 1024);
  }
  __syncthreads();

  for (int kb = 0; kb < 10; ++kb) {
    const int b = kb & 1;
    const char* kbuf = smem + b * 16384;
    const char* vbuf = kbuf + 8192;

    if (kb < 9) {
      char* kdst = smem + (b ^ 1) * 16384 + (w * 16) * 128;
      char* vdst = kdst + 8192;
      load_lds16(ksrc + (size_t)((kb + 1) * 64) * 1024, kdst);
      load_lds16(ksrc + (size_t)((kb + 1) * 64 + 8) * 1024, kdst + 1024);
      load_lds16(vsrc + (kb + 1) * 64, vdst);
      load_lds16(vsrc + 8 * SPAD + (kb + 1) * 64, vdst + 1024);
    }

    f32x4 s4[2][4];
    #pragma unroll
    for (int half = 0; half < 2; ++half)
      #pragma unroll
      for (int cf = 0; cf < 4; ++cf) s4[half][cf] = (f32x4)0.0f;
    #pragma unroll
    for (int kk = 0; kk < 2; ++kk)
      #pragma unroll
      for (int cf = 0; cf < 4; ++cf) {
        const bf16x8 af = *(const bf16x8*)(kbuf + (cf * 16 + fr) * 128 + ((kk * 64 + g * 16) ^ sw));
        s4[0][cf] = __builtin_amdgcn_mfma_f32_16x16x32_bf16(af, bq[0][kk], s4[0][cf], 0, 0, 0);
        s4[1][cf] = __builtin_amdgcn_mfma_f32_16x16x32_bf16(af, bq[1][kk], s4[1][cf], 0, 0, 0);
      }

    if (kb == 9) {
      #pragma unroll
      for (int half = 0; half < 2; ++half) {
        #pragma unroll
        for (int cf = 0; cf < 4; ++cf)
          #pragma unroll
          for (int r = 0; r < 4; ++r)
            if (cf != 0 || r != 0) s4[half][cf][r] = -__builtin_inff();
        s4[half][0][0] = (g == 0) ? s4[half][0][0] : -__builtin_inff();
      }
    }

    bf16x8 ap[2][2];
    #pragma unroll
    for (int half = 0; half < 2; ++half) {
      float sum = 0.0f;
      #pragma unroll
      for (int cf = 0; cf < 4; ++cf)
        #pragma unroll
        for (int r = 0; r < 4; ++r) {
          const float p = __builtin_amdgcn_exp2f(s4[half][cf][r]);
          s4[half][cf][r] = p;
          sum += p;
        }
      sum += __shfl_xor(sum, 16);
      sum += __shfl_xor(sum, 32);
      l_run[half] += sum;

      unsigned int pka[4], pkb[4];
      #pragma unroll
      for (int cf = 0; cf < 4; ++cf) {
        asm("v_cvt_pk_bf16_f32 %0, %1, %2" : "=v"(pka[cf]) : "v"(s4[half][cf][0]), "v"(s4[half][cf][1]));
        asm("v_cvt_pk_bf16_f32 %0, %1, %2" : "=v"(pkb[cf]) : "v"(s4[half][cf][2]), "v"(s4[half][cf][3]));
      }
      #pragma unroll
      for (int kk = 0; kk < 2; ++kk) {
        unsigned int a0 = pka[2 * kk], b0 = pka[2 * kk + 1];
        unsigned int a1 = pkb[2 * kk], b1 = pkb[2 * kk + 1];
        asm("v_permlane32_swap_b32 %0, %1" : "+v"(a0), "+v"(b0));
        asm("v_permlane16_swap_b32 %0, %1" : "+v"(a0), "+v"(b0));
        asm("v_permlane32_swap_b32 %0, %1" : "+v"(a1), "+v"(b1));
        asm("v_permlane16_swap_b32 %0, %1" : "+v"(a1), "+v"(b1));
        union { unsigned int i[4]; bf16x8 v; } u;
        u.i[0] = a0; u.i[1] = a1; u.i[2] = b0; u.i[3] = b1;
        ap[half][kk] = u.v;
      }
    }

    #pragma unroll
    for (int kk = 0; kk < 2; ++kk)
      #pragma unroll
      for (int cf = 0; cf < 4; ++cf) {
        const bf16x8 bv = *(const bf16x8*)(vbuf + (cf * 16 + fr) * 128 + ((kk * 64 + g * 16) ^ sw));
        acc[0][cf] = __builtin_amdgcn_mfma_f32_16x16x32_bf16(ap[0][kk], bv, acc[0][cf], 0, 0, 0);
        acc[1][cf] = __builtin_amdgcn_mfma_f32_16x16x32_bf16(ap[1][kk], bv, acc[1][cf], 0, 0, 0);
      }

    __syncthreads();
  }

  #pragma unroll
  for (int half = 0; half < 2; ++half) {
    const float rcp = 1.0f / l_run[half];
    #pragma unroll
    for (int r = 0; r < 4; ++r) {
      const float rr = __shfl(rcp, g * 4 + r);
      const int qg = qb * 128 + half * 64 + w * 16 + g * 4 + r;
      if (qg < SEQ) {
        #pragma unroll
        for (int cf = 0; cf < 4; ++cf)
          out[(rowbase + qg) * 1024 + h * 64 + cf * 16 + fr] = f2bf(acc[half][cf][r] * rr);
      }
    }
  }
}

extern "C" void kernel_launch(void* const* d_in, const int* in_sizes, int n_in,
                              void* d_out, int out_size, void* d_ws, size_t ws_size,
                              hipStream_t stream) {
  const float* x     = (const float*)d_in[0];
  const float* ln_g  = (const float*)d_in[1];
  const float* ln_b  = (const float*)d_in[2];
  const float* w_in  = (const float*)d_in[3];
  const float* b_in  = (const float*)d_in[4];
  const float* w_out = (const float*)d_in[5];
  const float* b_out = (const float*)d_in[6];

  unsigned short* z    = (unsigned short*)d_ws;            // [MPAD][1024] bf16; reused as attn_out
  unsigned short* qbuf = z + (size_t)MPAD * 1024;          // [MPAD][1024] bf16 (q = k, pre-scaled)
  unsigned short* vt   = qbuf + (size_t)MPAD * 1024;       // [32*1024][640] bf16 (V^T)
  unsigned short* wqv  = vt + (size_t)512 * 64 * SPAD;     // [2048][1024] bf16
  unsigned short* wo   = wqv + (size_t)2048 * 1024;        // [1024][1024] bf16

  ln_kernel<<<MPAD, 256, 0, stream>>>(x, ln_g, ln_b, z);
  conv_kernel<<<4096, 256, 0, stream>>>(w_in, w_out, wqv, wo, vt);
  gemm_kernel<0><<<1160, 256, 0, stream>>>(z, wqv, b_in, qbuf);
  gemm_kernel<2><<<1160, 256, 0, stream>>>(wqv + (size_t)1024 * 1024, z, b_in + 2048, vt);
  attn_kernel<<<2560, 256, 0, stream>>>(qbuf, vt, z);
  gemm_kernel<1><<<1160, 256, 0, stream>>>(z, wo, b_out, (float*)d_out);
}

// Round 9
// 250.654 us; speedup vs baseline: 1.1427x; 1.1427x over previous
//
#include <hip/hip_runtime.h>
#include <stdint.h>

typedef short bf16x8 __attribute__((ext_vector_type(8)));
typedef float f32x4 __attribute__((ext_vector_type(4)));
typedef unsigned int uint4v __attribute__((ext_vector_type(4)));
typedef unsigned short ushort4v __attribute__((ext_vector_type(4)));
typedef float float4v __attribute__((ext_vector_type(4)));

#define MROWS 18464      // 32*577
#define SEQ   577
#define CDIM  1024
#define SPAD  640
#define W1ELEMS (2048*1024)
#define W2ELEMS (1024*1024)
#define SQC 0.42466089f   // sqrt(0.125 * log2(e)); applied to q AND k (same buffer)

__device__ __forceinline__ unsigned short f2bf(float f) {
  unsigned int u = __float_as_uint(f);
  u += 0x7fffu + ((u >> 16) & 1u);   // RNE
  return (unsigned short)(u >> 16);
}

__device__ __forceinline__ void load_lds16(const void* g, void* lds) {
  __builtin_amdgcn_global_load_lds(
      (const __attribute__((address_space(1))) unsigned int*)(uint64_t)(uintptr_t)g,
      (__attribute__((address_space(3))) unsigned int*)(unsigned int)(uintptr_t)lds,
      16, 0, 0);
}

// ---------------- LayerNorm: x fp32 -> z bf16 (MROWS rows, no pad) ----------------
__global__ __launch_bounds__(256) void ln_kernel(const float* __restrict__ x,
                                                 const float* __restrict__ g,
                                                 const float* __restrict__ b,
                                                 unsigned short* __restrict__ z) {
  const int row = blockIdx.x;
  const int t = threadIdx.x;
  const float4v v = *(const float4v*)(x + (size_t)row * CDIM + t * 4);
  float s  = v[0] + v[1] + v[2] + v[3];
  float ss = v[0]*v[0] + v[1]*v[1] + v[2]*v[2] + v[3]*v[3];
  #pragma unroll
  for (int off = 1; off < 64; off <<= 1) { s += __shfl_xor(s, off); ss += __shfl_xor(ss, off); }
  __shared__ float rs[4], rss[4];
  const int w = t >> 6, l = t & 63;
  if (l == 0) { rs[w] = s; rss[w] = ss; }
  __syncthreads();
  s = rs[0] + rs[1] + rs[2] + rs[3];
  ss = rss[0] + rss[1] + rss[2] + rss[3];
  const float mu = s * (1.0f / CDIM);
  const float var = ss * (1.0f / CDIM) - mu * mu;
  const float rstd = rsqrtf(var + 1e-5f);
  const float4v gv = *(const float4v*)(g + t * 4);
  const float4v bv = *(const float4v*)(b + t * 4);
  ushort4v o;
  #pragma unroll
  for (int j = 0; j < 4; ++j) o[j] = f2bf((v[j] - mu) * rstd * gv[j] + bv[j]);
  *(ushort4v*)(z + (size_t)row * CDIM + t * 4) = o;
}

// -------- pack+convert weights + zero vt's seq-pad columns --------
__global__ __launch_bounds__(256) void conv_kernel(const float* __restrict__ w_in,
                                                   const float* __restrict__ w_out,
                                                   unsigned short* __restrict__ wqv,
                                                   unsigned short* __restrict__ wo,
                                                   unsigned short* __restrict__ vt) {
  const int idx = blockIdx.x * 256 + threadIdx.x;
  const int e = idx * 4;
  if (e < W1ELEMS) {
    const int row = e >> 10;
    const int srow = row < 1024 ? row : row + 1024;
    const float4v v = *(const float4v*)(w_in + (size_t)srow * 1024 + (e & 1023));
    ushort4v o;
    #pragma unroll
    for (int j = 0; j < 4; ++j) o[j] = f2bf(v[j]);
    *(ushort4v*)(wqv + e) = o;
  } else if (e < W1ELEMS + W2ELEMS) {
    const int e2 = e - W1ELEMS;
    const float4v v = *(const float4v*)(w_out + e2);
    ushort4v o;
    #pragma unroll
    for (int j = 0; j < 4; ++j) o[j] = f2bf(v[j]);
    *(ushort4v*)(wo + e2) = o;
  } else {
    // zero vt[row][576..640) for all 32768 rows
    const int pidx = idx - (W1ELEMS + W2ELEMS) / 4;   // 0..262143
    const int ic = pidx >> 3, part = pidx & 7;
    *(uint4v*)(vt + (size_t)ic * SPAD + 576 + part * 8) = (uint4v)0u;
  }
}

// ---------------- 256x256-tile GEMM, 8 waves (2M x 4N), BK=64, dbuf 2-phase ----------------
// D[m][n] = sum_k A[m][k]*B[n][k] (+bias). A rows clamped to MROWS-1 (pad-free A).
// MODE 0 (qv): 584 blocks, B=wqv[2048][1024]; n0<1024 -> q out bf16 xSQC to qout;
//              n0>=1024 -> v^T out to vt[(img*1024+ch)*640+s].
// MODE 1 (proj): 292 blocks, B=wo[1024][1024]; fp32 out + bias, row<MROWS guard.
template<int MODE>
__global__ __launch_bounds__(512, 2) void gemm256(const unsigned short* __restrict__ A,
                                                  const unsigned short* __restrict__ B,
                                                  const float* __restrict__ bias,
                                                  void* __restrict__ outp,
                                                  unsigned short* __restrict__ vtout) {
  __shared__ char smem[131072];  // buf b at b*65536: A [256][64] @0 (32KB), B @32768
  const int t = threadIdx.x;
  const int w = t >> 6, l = t & 63;
  int p, c;
  if constexpr (MODE == 0) {
    const int L = (blockIdx.x & 7) * 73 + (blockIdx.x >> 3);   // bijective: 584=8*73
    p = L >> 3; c = L & 7;
  } else {
    const int xcd = blockIdx.x & 7, j = blockIdx.x >> 3;       // 292 = 4*37 + 4*36
    const int L = (xcd < 4 ? xcd * 37 : 148 + (xcd - 4) * 36) + j;
    p = L >> 2; c = L & 3;
  }
  const int m0 = p * 256;
  const int n0 = c * 256;
  const int wm = w >> 2, wn = w & 3;
  const int g4 = (l >> 4) * 4;
  const int fr = l & 15;
  const int fb = (l >> 4) * 16;
  const int sw = (l & 7) << 4;

  f32x4 acc[8][4];
  #pragma unroll
  for (int i = 0; i < 8; ++i)
    #pragma unroll
    for (int j = 0; j < 4; ++j) acc[i][j] = (f32x4)0.0f;

  // staging: 128B rows, pre-swizzled source, per-lane A-row clamp (pad-free A buffer)
  const int srow = l >> 3;
  const int scol = ((((l & 7) * 16) ^ ((srow & 7) << 4)) >> 1);
  const unsigned short* Ap[4];
  const unsigned short* Bp[4];
  #pragma unroll
  for (int c2 = 0; c2 < 4; ++c2) {
    int arow = m0 + w * 32 + c2 * 8 + srow;
    if (arow > MROWS - 1) arow = MROWS - 1;
    Ap[c2] = A + (size_t)arow * 1024 + scol;
    Bp[c2] = B + (size_t)(n0 + w * 32 + c2 * 8 + srow) * 1024 + scol;
  }

  #define STG(kt, buf)                                                     \
    {                                                                      \
      char* const d_ = smem + (buf) * 65536 + w * 4096;                    \
      const int k0_ = (kt) * 64;                                           \
      _Pragma("unroll")                                                    \
      for (int c2 = 0; c2 < 4; ++c2) {                                     \
        load_lds16(Ap[c2] + k0_, d_ + c2 * 1024);                          \
        load_lds16(Bp[c2] + k0_, d_ + 32768 + c2 * 1024);                  \
      }                                                                    \
    }

  STG(0, 0)
  __syncthreads();

  for (int kb = 0; kb < 16; ++kb) {
    const int b = kb & 1;
    if (kb < 15) STG(kb + 1, b ^ 1)
    const char* Ab = smem + b * 65536;
    const char* Bb = Ab + 32768;
    #pragma unroll
    for (int kk = 0; kk < 2; ++kk) {
      bf16x8 af[8], bfr[4];
      #pragma unroll
      for (int i = 0; i < 8; ++i)
        af[i] = *(const bf16x8*)(Ab + (wm * 128 + i * 16 + fr) * 128 + ((kk * 64 + fb) ^ sw));
      #pragma unroll
      for (int j = 0; j < 4; ++j)
        bfr[j] = *(const bf16x8*)(Bb + (wn * 64 + j * 16 + fr) * 128 + ((kk * 64 + fb) ^ sw));
      #pragma unroll
      for (int i = 0; i < 8; ++i)
        #pragma unroll
        for (int j = 0; j < 4; ++j)
          acc[i][j] = __builtin_amdgcn_mfma_f32_16x16x32_bf16(af[i], bfr[j], acc[i][j], 0, 0, 0);
    }
    __syncthreads();
  }
  #undef STG

  if constexpr (MODE == 0) {
    unsigned short* sm = (unsigned short*)smem;   // [128][264] b16 = 67584B per pass
    const bool isq = (n0 < 1024);
    const float* bb = isq ? (bias + n0) : (bias + 1024 + n0);
    const float scl = isq ? SQC : 1.0f;
    float bcol[4];
    #pragma unroll
    for (int j = 0; j < 4; ++j) bcol[j] = bb[wn * 64 + j * 16 + fr];
    for (int pass = 0; pass < 2; ++pass) {
      if (wm == pass) {
        #pragma unroll
        for (int i = 0; i < 8; ++i)
          #pragma unroll
          for (int j = 0; j < 4; ++j)
            #pragma unroll
            for (int r = 0; r < 4; ++r)
              sm[(i * 16 + g4 + r) * 264 + wn * 64 + j * 16 + fr] =
                  f2bf((acc[i][j][r] + bcol[j]) * scl);
      }
      __syncthreads();
      if (isq) {
        unsigned short* o = (unsigned short*)outp;
        #pragma unroll
        for (int it = 0; it < 8; ++it) {
          const int cid = it * 512 + t;
          const int row = cid >> 5, ch = cid & 31;
          const int grow = m0 + pass * 128 + row;
          if (grow < MROWS)
            *(uint4v*)(o + (size_t)grow * 1024 + n0 + ch * 8) =
                *(const uint4v*)(sm + row * 264 + ch * 8);
        }
      } else {
        const int rowloc = t & 127, chb = t >> 7;   // chb 0..3, 64 channels each
        const int token = m0 + pass * 128 + rowloc;
        if (token < MROWS) {
          const unsigned int nimg = (unsigned int)token / 577u;
          const int s = token - (int)(nimg * 577u);
          unsigned short* op =
              vtout + ((size_t)nimg * 1024 + (n0 - 1024) + chb * 64) * SPAD + s;
          const unsigned short* sp = sm + rowloc * 264 + chb * 64;
          #pragma unroll 8
          for (int it = 0; it < 64; ++it)
            op[(size_t)it * SPAD] = sp[it];
        }
      }
      __syncthreads();
    }
  } else {  // proj fp32: four 64-row passes, [64][260] f32 = 66560B
    float* smf = (float*)smem;
    float bcol[4];
    #pragma unroll
    for (int j = 0; j < 4; ++j) bcol[j] = bias[n0 + wn * 64 + j * 16 + fr];
    float* o = (float*)outp;
    for (int q4 = 0; q4 < 4; ++q4) {
      if (wm == (q4 >> 1)) {
        const int i0 = (q4 & 1) * 4;
        #pragma unroll
        for (int i2 = 0; i2 < 4; ++i2)
          #pragma unroll
          for (int j = 0; j < 4; ++j)
            #pragma unroll
            for (int r = 0; r < 4; ++r)
              smf[(i2 * 16 + g4 + r) * 260 + wn * 64 + j * 16 + fr] =
                  acc[i0 + i2][j][r] + bcol[j];
      }
      __syncthreads();
      #pragma unroll
      for (int it = 0; it < 8; ++it) {
        const int cid = it * 512 + t;
        const int row = cid >> 6, ch = cid & 63;
        const int grow = m0 + q4 * 64 + row;
        if (grow < MROWS)
          *(float4v*)(o + (size_t)grow * 1024 + n0 + ch * 4) =
              *(const float4v*)(smf + row * 260 + ch * 4);
      }
      __syncthreads();
    }
  }
}

// ---------------- flash attention, k = q ('qq'), no-max softmax ----------------
// QBLK=128: each wave owns 2x16 q-rows; K/V LDS fragments read ONCE feed both
// halves. Double-buffered staging. 1-D grid 2560, XCD-chunked.
__global__ __launch_bounds__(256) void attn_kernel(const unsigned short* __restrict__ qbuf,
                                                   const unsigned short* __restrict__ vt,
                                                   unsigned short* __restrict__ out) {
  __shared__ char smem[32768];  // buf b at b*16384: K 8KB, V^T 8KB
  const int t = threadIdx.x, w = t >> 6, l = t & 63;
  const int g = l >> 4, fr = l & 15;
  const int bid = blockIdx.x;
  const int xcd = bid & 7, idx = bid >> 3;
  const int nhl = idx / 5;
  const int qb = idx - nhl * 5;
  const int nh = xcd * 64 + nhl;
  const int n = nh >> 4, h = nh & 15;
  const size_t rowbase = (size_t)n * SEQ;
  const int sw = (l & 7) << 4;

  bf16x8 bq[2][2];
  #pragma unroll
  for (int half = 0; half < 2; ++half) {
    const unsigned short* qp =
        qbuf + (rowbase + qb * 128 + half * 64 + w * 16 + fr) * 1024 + h * 64 + g * 8;
    bq[half][0] = *(const bf16x8*)qp;
    bq[half][1] = *(const bf16x8*)(qp + 32);
  }

  const int srow = l >> 3;
  const int scolE = ((((l & 7) * 16) ^ ((srow & 7) << 4)) >> 1);
  const unsigned short* ksrc = qbuf + (rowbase + w * 16 + srow) * 1024 + h * 64 + scolE;
  const unsigned short* vsrc = vt + ((size_t)nh * 64 + w * 16 + srow) * SPAD + scolE;

  f32x4 acc[2][4];
  #pragma unroll
  for (int half = 0; half < 2; ++half)
    #pragma unroll
    for (int cf = 0; cf < 4; ++cf) acc[half][cf] = (f32x4)0.0f;
  float l_run[2] = {0.0f, 0.0f};

  {
    char* kdst = smem + (w * 16) * 128;
    char* vdst = smem + 8192 + (w * 16) * 128;
    load_lds16(ksrc, kdst);
    load_lds16(ksrc + (size_t)8 * 1024, kdst + 1024);
    load_lds16(vsrc, vdst);
    load_lds16(vsrc + 8 * SPAD, vdst + 1024);
  }
  __syncthreads();

  for (int kb = 0; kb < 10; ++kb) {
    const int b = kb & 1;
    const char* kbuf = smem + b * 16384;
    const char* vbuf = kbuf + 8192;

    if (kb < 9) {
      char* kdst = smem + (b ^ 1) * 16384 + (w * 16) * 128;
      char* vdst = kdst + 8192;
      load_lds16(ksrc + (size_t)((kb + 1) * 64) * 1024, kdst);
      load_lds16(ksrc + (size_t)((kb + 1) * 64 + 8) * 1024, kdst + 1024);
      load_lds16(vsrc + (kb + 1) * 64, vdst);
      load_lds16(vsrc + 8 * SPAD + (kb + 1) * 64, vdst + 1024);
    }

    f32x4 s4[2][4];
    #pragma unroll
    for (int half = 0; half < 2; ++half)
      #pragma unroll
      for (int cf = 0; cf < 4; ++cf) s4[half][cf] = (f32x4)0.0f;
    #pragma unroll
    for (int kk = 0; kk < 2; ++kk)
      #pragma unroll
      for (int cf = 0; cf < 4; ++cf) {
        const bf16x8 af = *(const bf16x8*)(kbuf + (cf * 16 + fr) * 128 + ((kk * 64 + g * 16) ^ sw));
        s4[0][cf] = __builtin_amdgcn_mfma_f32_16x16x32_bf16(af, bq[0][kk], s4[0][cf], 0, 0, 0);
        s4[1][cf] = __builtin_amdgcn_mfma_f32_16x16x32_bf16(af, bq[1][kk], s4[1][cf], 0, 0, 0);
      }

    if (kb == 9) {
      #pragma unroll
      for (int half = 0; half < 2; ++half) {
        #pragma unroll
        for (int cf = 0; cf < 4; ++cf)
          #pragma unroll
          for (int r = 0; r < 4; ++r)
            if (cf != 0 || r != 0) s4[half][cf][r] = -__builtin_inff();
        s4[half][0][0] = (g == 0) ? s4[half][0][0] : -__builtin_inff();
      }
    }

    bf16x8 ap[2][2];
    #pragma unroll
    for (int half = 0; half < 2; ++half) {
      float sum = 0.0f;
      #pragma unroll
      for (int cf = 0; cf < 4; ++cf)
        #pragma unroll
        for (int r = 0; r < 4; ++r) {
          const float p2 = __builtin_amdgcn_exp2f(s4[half][cf][r]);
          s4[half][cf][r] = p2;
          sum += p2;
        }
      sum += __shfl_xor(sum, 16);
      sum += __shfl_xor(sum, 32);
      l_run[half] += sum;

      unsigned int pka[4], pkb[4];
      #pragma unroll
      for (int cf = 0; cf < 4; ++cf) {
        asm("v_cvt_pk_bf16_f32 %0, %1, %2" : "=v"(pka[cf]) : "v"(s4[half][cf][0]), "v"(s4[half][cf][1]));
        asm("v_cvt_pk_bf16_f32 %0, %1, %2" : "=v"(pkb[cf]) : "v"(s4[half][cf][2]), "v"(s4[half][cf][3]));
      }
      #pragma unroll
      for (int kk = 0; kk < 2; ++kk) {
        unsigned int a0 = pka[2 * kk], b0 = pka[2 * kk + 1];
        unsigned int a1 = pkb[2 * kk], b1 = pkb[2 * kk + 1];
        asm("v_permlane32_swap_b32 %0, %1" : "+v"(a0), "+v"(b0));
        asm("v_permlane16_swap_b32 %0, %1" : "+v"(a0), "+v"(b0));
        asm("v_permlane32_swap_b32 %0, %1" : "+v"(a1), "+v"(b1));
        asm("v_permlane16_swap_b32 %0, %1" : "+v"(a1), "+v"(b1));
        union { unsigned int i[4]; bf16x8 v; } u;
        u.i[0] = a0; u.i[1] = a1; u.i[2] = b0; u.i[3] = b1;
        ap[half][kk] = u.v;
      }
    }

    #pragma unroll
    for (int kk = 0; kk < 2; ++kk)
      #pragma unroll
      for (int cf = 0; cf < 4; ++cf) {
        const bf16x8 bv = *(const bf16x8*)(vbuf + (cf * 16 + fr) * 128 + ((kk * 64 + g * 16) ^ sw));
        acc[0][cf] = __builtin_amdgcn_mfma_f32_16x16x32_bf16(ap[0][kk], bv, acc[0][cf], 0, 0, 0);
        acc[1][cf] = __builtin_amdgcn_mfma_f32_16x16x32_bf16(ap[1][kk], bv, acc[1][cf], 0, 0, 0);
      }

    __syncthreads();
  }

  #pragma unroll
  for (int half = 0; half < 2; ++half) {
    const float rcp = 1.0f / l_run[half];
    #pragma unroll
    for (int r = 0; r < 4; ++r) {
      const float rr = __shfl(rcp, g * 4 + r);
      const int qg = qb * 128 + half * 64 + w * 16 + g * 4 + r;
      if (qg < SEQ) {
        #pragma unroll
        for (int cf = 0; cf < 4; ++cf)
          out[(rowbase + qg) * 1024 + h * 64 + cf * 16 + fr] = f2bf(acc[half][cf][r] * rr);
      }
    }
  }
}

extern "C" void kernel_launch(void* const* d_in, const int* in_sizes, int n_in,
                              void* d_out, int out_size, void* d_ws, size_t ws_size,
                              hipStream_t stream) {
  const float* x     = (const float*)d_in[0];
  const float* ln_g  = (const float*)d_in[1];
  const float* ln_b  = (const float*)d_in[2];
  const float* w_in  = (const float*)d_in[3];
  const float* b_in  = (const float*)d_in[4];
  const float* w_out = (const float*)d_in[5];
  const float* b_out = (const float*)d_in[6];

  unsigned short* z    = (unsigned short*)d_ws;            // [MROWS][1024] bf16; reused as attn_out
  unsigned short* qbuf = z + (size_t)MROWS * 1024;         // [MROWS][1024] bf16 (q = k, pre-scaled)
  unsigned short* vt   = qbuf + (size_t)MROWS * 1024;      // [32*1024][640] bf16 (V^T)
  unsigned short* wqv  = vt + (size_t)512 * 64 * SPAD;     // [2048][1024] bf16
  unsigned short* wo   = wqv + (size_t)2048 * 1024;        // [1024][1024] bf16

  ln_kernel<<<MROWS, 256, 0, stream>>>(x, ln_g, ln_b, z);
  conv_kernel<<<4096, 256, 0, stream>>>(w_in, w_out, wqv, wo, vt);
  gemm256<0><<<584, 512, 0, stream>>>(z, wqv, b_in, qbuf, vt);
  attn_kernel<<<2560, 256, 0, stream>>>(qbuf, vt, z);
  gemm256<1><<<292, 512, 0, stream>>>(z, wo, b_out, d_out, nullptr);
}